// Round 14
// baseline (133.590 us; speedup 1.0000x reference)
//
#include <hip/hip_runtime.h>
#include <math.h>

#define HDIM 512
#define NCH1 96              // GEMM1 A-chunks (16 hidden rows each), 2 per t
#define NCH2 48              // t-chunks of 32 hidden
#define EPS_DIAG 0.1f

typedef __fp16 h2 __attribute__((ext_vector_type(2)));
typedef __fp16 h8 __attribute__((ext_vector_type(8)));
typedef float f32x4 __attribute__((ext_vector_type(4)));
typedef unsigned int u32x4 __attribute__((ext_vector_type(4)));

__device__ __forceinline__ h2 f2h2(float a, float b) {
    return __builtin_amdgcn_cvt_pkrtz(a, b);   // a->low, b->high
}

// Scalar-f32 odd degree-7 poly tanh on clamp(x,-2,2): 6 guaranteed-single
// VOP3 instrs (fmed3 + mul + 3 fma + mul). R12/R13 evidence says the packed
// __fp16 elementwise path scalarizes (~2x instrs) — f32 avoids that risk.
__device__ __forceinline__ float tanh1(float x) {
    const float C0 = 0.993654f;
    const float C1 = -0.29463f;
    const float C2 = 0.0695331f;
    const float C3 = -0.00696328f;
    const float t = __builtin_amdgcn_fmed3f(x, -2.0f, 2.0f);
    const float u = t * t;
    float p = fmaf(C3, u, C2);
    p = fmaf(p, u, C1);
    p = fmaf(p, u, C0);
    return t * p;
}

// Combined first layer W1c[k][hid]: hid in [0,512)=m-net, [512,1024)=g, [1024,1536)=k.
// x vector: [q0,q1,q2,s0,s1,s2,d0,d1,d2,1, 0..] (bias folded at k=9).
__device__ __forceinline__ float w1c_at(int k, int hid,
    const float* W1m, const float* b1m, const float* W1g, const float* b1g,
    const float* W1k, const float* b1k)
{
    if (hid < 512)  { if (k < 3) return W1m[k*HDIM + hid]; if (k == 9) return b1m[hid]; return 0.f; }
    if (hid < 1024) { const int h = hid - 512;
                      if (k < 3) return W1g[k*HDIM + h];  if (k == 9) return b1g[h];  return 0.f; }
    const int h = hid - 1024;
    if (k < 9) return W1k[k*HDIM + h]; if (k == 9) return b1k[h]; return 0.f;
}

// IDENTICAL layout to R11/R12 (verified: absmax 0.25).
// frag1 chunk c (c=2t+phase): A[m=lane&15][k=quad*8+j], hid(c,m)=32t+8*(m>>2)+(m&3)+4*phase.
// frag2 chunk t: A[m=out(lane&15)][k'=quad*8+j] = W2c[32t + quad*8+j][out].
__global__ void pack_frags(const float* __restrict__ W1m, const float* __restrict__ b1m,
                           const float* __restrict__ W2m,
                           const float* __restrict__ W1g, const float* __restrict__ b1g,
                           const float* __restrict__ W2g,
                           const float* __restrict__ W1k, const float* __restrict__ b1k,
                           const float* __restrict__ W2k,
                           __fp16* __restrict__ frag)
{
    const int tid = blockIdx.x * blockDim.x + threadIdx.x;
    if (tid >= (NCH1 + NCH2) * 64) return;
    const int c = tid >> 6, l = tid & 63;
    const int m = l & 15, kq = l >> 4;
    __fp16* dst = frag + (size_t)tid * 8;
    if (c < NCH1) {
        const int t = c >> 1, phase = c & 1;
        const int hid = 32*t + 8*(m >> 2) + (m & 3) + 4*phase;
        #pragma unroll
        for (int j = 0; j < 8; ++j) {
            const int k = kq*8 + j;
            dst[j] = (__fp16)((k < 10) ? w1c_at(k, hid, W1m, b1m, W1g, b1g, W1k, b1k) : 0.f);
        }
    } else {
        const int t = c - NCH1;
        #pragma unroll
        for (int j = 0; j < 8; ++j) {
            const int hid = 32*t + kq*8 + j;
            float v = 0.f;
            if (hid < 512)       { if (m < 9)             v = W2m[hid*9 + m]; }
            else if (hid < 1024) { if (m >= 9 && m < 12)  v = W2g[(hid-512)*3 + (m-9)]; }
            else                 { if (m >= 12 && m < 15) v = W2k[(hid-1024)*3 + (m-12)]; }
            dst[j] = (__fp16)v;
        }
    }
}

__global__ __launch_bounds__(256, 4) void dyn_kernel(
    const __fp16* __restrict__ frag,
    const float* __restrict__ q, const float* __restrict__ q_dot,
    const float* __restrict__ s, const float* __restrict__ s_Ddot,
    const float* __restrict__ tau,
    const float* __restrict__ fv, const float* __restrict__ fc,
    const float* __restrict__ b2m, const float* __restrict__ b2g,
    const float* __restrict__ b2k,
    float* __restrict__ out, int n)
{
    __shared__ float ebuf[4][32][20];   // epilogue gather; stride 20 -> aligned b128, no conflicts

    const int lane = threadIdx.x & 63;
    const int w    = threadIdx.x >> 6;
    const int col  = lane & 15;
    const int quad = lane >> 4;
    const int base32 = (blockIdx.x * 4 + w) * 32;   // 32 samples per wave (2 tiles)

    // B-operands for GEMM1': B[k=quad*8+j][n=sample=col], one per tile.
    h8 ax0, ax1;
    {
        int sm = base32 + col; if (sm >= n) sm = n - 1;
        const float q0 = q[3*sm+0], q1 = q[3*sm+1], q2 = q[3*sm+2];
        const float s0 = s[3*sm+0], s1 = s[3*sm+1], s2 = s[3*sm+2];
        const float d0 = s_Ddot[3*sm+0], d1 = s_Ddot[3*sm+1], d2 = s_Ddot[3*sm+2];
        const bool z0 = (quad == 0), z1 = (quad == 1);
        ax0[0] = (__fp16)(z0 ? q0 : (z1 ? d2  : 0.f));
        ax0[1] = (__fp16)(z0 ? q1 : (z1 ? 1.f : 0.f));
        ax0[2] = (__fp16)(z0 ? q2 : 0.f);
        ax0[3] = (__fp16)(z0 ? s0 : 0.f);
        ax0[4] = (__fp16)(z0 ? s1 : 0.f);
        ax0[5] = (__fp16)(z0 ? s2 : 0.f);
        ax0[6] = (__fp16)(z0 ? d0 : 0.f);
        ax0[7] = (__fp16)(z0 ? d1 : 0.f);
    }
    {
        int sm = base32 + 16 + col; if (sm >= n) sm = n - 1;
        const float q0 = q[3*sm+0], q1 = q[3*sm+1], q2 = q[3*sm+2];
        const float s0 = s[3*sm+0], s1 = s[3*sm+1], s2 = s[3*sm+2];
        const float d0 = s_Ddot[3*sm+0], d1 = s_Ddot[3*sm+1], d2 = s_Ddot[3*sm+2];
        const bool z0 = (quad == 0), z1 = (quad == 1);
        ax1[0] = (__fp16)(z0 ? q0 : (z1 ? d2  : 0.f));
        ax1[1] = (__fp16)(z0 ? q1 : (z1 ? 1.f : 0.f));
        ax1[2] = (__fp16)(z0 ? q2 : 0.f);
        ax1[3] = (__fp16)(z0 ? s0 : 0.f);
        ax1[4] = (__fp16)(z0 ? s1 : 0.f);
        ax1[5] = (__fp16)(z0 ? s2 : 0.f);
        ax1[6] = (__fp16)(z0 ? d0 : 0.f);
        ax1[7] = (__fp16)(z0 ? d1 : 0.f);
    }

    const f32x4 zero4 = {0.f, 0.f, 0.f, 0.f};
    f32x4 acc0 = zero4, acc1 = zero4;

    const h8* p1 = (const h8*)frag + lane;                       // frag1, chunk=64 h8
    const h8* p2 = (const h8*)frag + (size_t)NCH1 * 64 + lane;   // frag2

// One t-step: per tile 2 GEMM1' MFMAs -> 8 scalar-f32 tanh -> 4 packs ->
// 1 GEMM2 MFMA. Two tiles share the weight fragments. Zero LDS in loop.
#define BODY(W1A, W1B, W2V) do {                                              \
        f32x4 pa0 = __builtin_amdgcn_mfma_f32_16x16x32_f16((W1A), ax0, zero4, 0, 0, 0); \
        f32x4 pb0 = __builtin_amdgcn_mfma_f32_16x16x32_f16((W1B), ax0, zero4, 0, 0, 0); \
        f32x4 pa1 = __builtin_amdgcn_mfma_f32_16x16x32_f16((W1A), ax1, zero4, 0, 0, 0); \
        f32x4 pb1 = __builtin_amdgcn_mfma_f32_16x16x32_f16((W1B), ax1, zero4, 0, 0, 0); \
        u32x4 uv;                                                             \
        uv[0] = __builtin_bit_cast(unsigned int, f2h2(tanh1(pa0[0]), tanh1(pa0[1]))); \
        uv[1] = __builtin_bit_cast(unsigned int, f2h2(tanh1(pa0[2]), tanh1(pa0[3]))); \
        uv[2] = __builtin_bit_cast(unsigned int, f2h2(tanh1(pb0[0]), tanh1(pb0[1]))); \
        uv[3] = __builtin_bit_cast(unsigned int, f2h2(tanh1(pb0[2]), tanh1(pb0[3]))); \
        acc0 = __builtin_amdgcn_mfma_f32_16x16x32_f16((W2V), __builtin_bit_cast(h8, uv), acc0, 0, 0, 0); \
        uv[0] = __builtin_bit_cast(unsigned int, f2h2(tanh1(pa1[0]), tanh1(pa1[1]))); \
        uv[1] = __builtin_bit_cast(unsigned int, f2h2(tanh1(pa1[2]), tanh1(pa1[3]))); \
        uv[2] = __builtin_bit_cast(unsigned int, f2h2(tanh1(pb1[0]), tanh1(pb1[1]))); \
        uv[3] = __builtin_bit_cast(unsigned int, f2h2(tanh1(pb1[2]), tanh1(pb1[3]))); \
        acc1 = __builtin_amdgcn_mfma_f32_16x16x32_f16((W2V), __builtin_bit_cast(h8, uv), acc1, 0, 0, 0); \
    } while (0)

    // Unroll-by-2 ping-pong prefetch; all offsets immediates (< 4096 B).
    h8 a0 = p1[0], b0 = p1[64], c0 = p2[0];
    int t = 0;
    for (; t < NCH2 - 2; t += 2) {
        h8 a1 = p1[128], b1 = p1[192], c1 = p2[64];
        p1 += 256; p2 += 128;
        BODY(a0, b0, c0);
        a0 = p1[0]; b0 = p1[64]; c0 = p2[0];
        BODY(a1, b1, c1);
    }
    {   // final pair (t = 46, 47): no t+2 prefetch -> no OOB reads
        h8 a1 = p1[128], b1 = p1[192], c1 = p2[64];
        BODY(a0, b0, c0);
        BODY(a1, b1, c1);
    }
#undef BODY

    // Epilogue: acc lane (col=sample, quad) holds outs {4q..4q+3}. One b128
    // deposit per tile per lane; lanes 0..31 gather their sample's 15 outputs.
    *(f32x4*)(&ebuf[w][col][4*quad])      = acc0;
    *(f32x4*)(&ebuf[w][16 + col][4*quad]) = acc1;
    asm volatile("s_waitcnt lgkmcnt(0)" ::: "memory");

    if (lane < 32) {
        const int i = base32 + lane;
        if (i < n) {
            const float* R = ebuf[w][lane];
            const float bM0 = R[0]  + b2m[0], bM1 = R[1]  + b2m[1], bM2 = R[2]  + b2m[2];
            const float bM3 = R[3]  + b2m[3], bM4 = R[4]  + b2m[4], bM5 = R[5]  + b2m[5];
            const float bM6 = R[6]  + b2m[6], bM7 = R[7]  + b2m[7], bM8 = R[8]  + b2m[8];
            const float bG0 = R[9]  + b2g[0], bG1 = R[10] + b2g[1], bG2 = R[11] + b2g[2];
            const float bK0 = R[12] + b2k[0], bK1 = R[13] + b2k[1], bK2 = R[14] + b2k[2];

            // M = Mraw @ Mraw^T + eps*I
            const float m00 = bM0*bM0 + bM1*bM1 + bM2*bM2 + EPS_DIAG;
            const float m01 = bM0*bM3 + bM1*bM4 + bM2*bM5;
            const float m02 = bM0*bM6 + bM1*bM7 + bM2*bM8;
            const float m11 = bM3*bM3 + bM4*bM4 + bM5*bM5 + EPS_DIAG;
            const float m12 = bM3*bM6 + bM4*bM7 + bM5*bM8;
            const float m22 = bM6*bM6 + bM7*bM7 + bM8*bM8 + EPS_DIAG;

            // rhs = -G + KAB - fv*q_dot - fc*sign(q_dot) + tau
            const float qd0 = q_dot[3*i+0], qd1 = q_dot[3*i+1], qd2 = q_dot[3*i+2];
            const float t0 = tau[3*i+0], t1 = tau[3*i+1], t2 = tau[3*i+2];
            const float fv0 = fv[0], fv1 = fv[1], fv2 = fv[2];
            const float fc0 = fc[0], fc1 = fc[1], fc2 = fc[2];
            const float sg0 = (qd0 > 0.f) ? 1.f : ((qd0 < 0.f) ? -1.f : 0.f);
            const float sg1 = (qd1 > 0.f) ? 1.f : ((qd1 < 0.f) ? -1.f : 0.f);
            const float sg2 = (qd2 > 0.f) ? 1.f : ((qd2 < 0.f) ? -1.f : 0.f);
            const float r0 = -bG0 + bK0 - fv0*qd0 - fc0*sg0 + t0;
            const float r1 = -bG1 + bK1 - fv1*qd1 - fc1*sg1 + t1;
            const float r2 = -bG2 + bK2 - fv2*qd2 - fc2*sg2 + t2;

            // Symmetric 3x3 inverse via adjugate (M SPD, det >= ~1e-3).
            const float c00 = m11*m22 - m12*m12;
            const float c01 = m02*m12 - m01*m22;
            const float c02 = m01*m12 - m02*m11;
            const float det = m00*c00 + m01*c01 + m02*c02;
            const float idet = 1.0f / det;
            const float i11 = m00*m22 - m02*m02;
            const float i12 = m01*m02 - m00*m12;
            const float i22 = m00*m11 - m01*m01;

            out[3*i+0] = (c00*r0 + c01*r1 + c02*r2) * idet;
            out[3*i+1] = (c01*r0 + i11*r1 + i12*r2) * idet;
            out[3*i+2] = (c02*r0 + i12*r1 + i22*r2) * idet;
        }
    }
}

extern "C" void kernel_launch(void* const* d_in, const int* in_sizes, int n_in,
                              void* d_out, int out_size, void* d_ws, size_t ws_size,
                              hipStream_t stream) {
    const float* q      = (const float*)d_in[0];
    const float* q_dot  = (const float*)d_in[1];
    const float* s      = (const float*)d_in[2];
    const float* s_Ddot = (const float*)d_in[3];
    const float* tau    = (const float*)d_in[4];
    const float* fv     = (const float*)d_in[5];
    const float* fc     = (const float*)d_in[6];
    const float* W1m    = (const float*)d_in[7];
    const float* b1m    = (const float*)d_in[8];
    const float* W2m    = (const float*)d_in[9];
    const float* b2m    = (const float*)d_in[10];
    const float* W1g    = (const float*)d_in[11];
    const float* b1g    = (const float*)d_in[12];
    const float* W2g    = (const float*)d_in[13];
    const float* b2g    = (const float*)d_in[14];
    const float* W1k    = (const float*)d_in[15];
    const float* b1k    = (const float*)d_in[16];
    const float* W2k    = (const float*)d_in[17];
    const float* b2k    = (const float*)d_in[18];
    float* out = (float*)d_out;
    __fp16* frag = (__fp16*)d_ws;   // (96+48)*64*8*2 = 147456 B

    const int n = in_sizes[0] / 3;  // B = 131072

    pack_frags<<<((NCH1 + NCH2) * 64 + 255) / 256, 256, 0, stream>>>(
        W1m, b1m, W2m, W1g, b1g, W2g, W1k, b1k, W2k, frag);

    const int blocks = (n + 127) / 128;   // 4 waves/block, 32 samples/wave
    dyn_kernel<<<blocks, 256, 0, stream>>>(frag, q, q_dot, s, s_Ddot, tau, fv, fc,
                                           b2m, b2g, b2k, out, n);
}

// Round 15
// 131.389 us; speedup vs baseline: 1.0168x; 1.0168x over previous
//
#include <hip/hip_runtime.h>
#include <math.h>

#define HDIM 512
#define NCH1 96              // GEMM1 A-chunks (16 hidden rows each), 2 per t
#define NCH2 48              // t-chunks of 32 hidden
#define NCHH 24              // t-chunks per wave (half of NCH2)
#define EPS_DIAG 0.1f

typedef __fp16 h2 __attribute__((ext_vector_type(2)));
typedef __fp16 h8 __attribute__((ext_vector_type(8)));
typedef float f32x4 __attribute__((ext_vector_type(4)));
typedef unsigned int u32x4 __attribute__((ext_vector_type(4)));

__device__ __forceinline__ h2 f2h2(float a, float b) {
    return __builtin_amdgcn_cvt_pkrtz(a, b);   // a->low, b->high
}

// Packed-f16 odd degree-7 poly tanh on clamp(x,-2,2). R14's A/B test proved
// this path emits true v_pk_* (busy-cycle ratio matched instr counts).
__device__ __forceinline__ h2 tanh2(h2 x) {
    const h2 HI = {(__fp16)2.0f,        (__fp16)2.0f};
    const h2 LO = {(__fp16)-2.0f,       (__fp16)-2.0f};
    const h2 C0 = {(__fp16)0.993654f,   (__fp16)0.993654f};
    const h2 C1 = {(__fp16)-0.29463f,   (__fp16)-0.29463f};
    const h2 C2 = {(__fp16)0.0695331f,  (__fp16)0.0695331f};
    const h2 C3 = {(__fp16)-0.00696328f,(__fp16)-0.00696328f};
    h2 t = __builtin_elementwise_min(__builtin_elementwise_max(x, LO), HI);
    h2 u = t * t;
    h2 p = __builtin_elementwise_fma(C3, u, C2);
    p = __builtin_elementwise_fma(p, u, C1);
    p = __builtin_elementwise_fma(p, u, C0);
    return t * p;
}

// Combined first layer W1c[k][hid]: hid in [0,512)=m-net, [512,1024)=g, [1024,1536)=k.
// x vector: [q0,q1,q2,s0,s1,s2,d0,d1,d2,1, 0..] (bias folded at k=9).
__device__ __forceinline__ float w1c_at(int k, int hid,
    const float* W1m, const float* b1m, const float* W1g, const float* b1g,
    const float* W1k, const float* b1k)
{
    if (hid < 512)  { if (k < 3) return W1m[k*HDIM + hid]; if (k == 9) return b1m[hid]; return 0.f; }
    if (hid < 1024) { const int h = hid - 512;
                      if (k < 3) return W1g[k*HDIM + h];  if (k == 9) return b1g[h];  return 0.f; }
    const int h = hid - 1024;
    if (k < 9) return W1k[k*HDIM + h]; if (k == 9) return b1k[h]; return 0.f;
}

// IDENTICAL layout to R11/R12 (verified: absmax 0.25).
// frag1 chunk c (c=2t+phase): A[m=lane&15][k=quad*8+j], hid(c,m)=32t+8*(m>>2)+(m&3)+4*phase.
// frag2 chunk t: A[m=out(lane&15)][k'=quad*8+j] = W2c[32t + quad*8+j][out].
__global__ void pack_frags(const float* __restrict__ W1m, const float* __restrict__ b1m,
                           const float* __restrict__ W2m,
                           const float* __restrict__ W1g, const float* __restrict__ b1g,
                           const float* __restrict__ W2g,
                           const float* __restrict__ W1k, const float* __restrict__ b1k,
                           const float* __restrict__ W2k,
                           __fp16* __restrict__ frag)
{
    const int tid = blockIdx.x * blockDim.x + threadIdx.x;
    if (tid >= (NCH1 + NCH2) * 64) return;
    const int c = tid >> 6, l = tid & 63;
    const int m = l & 15, kq = l >> 4;
    __fp16* dst = frag + (size_t)tid * 8;
    if (c < NCH1) {
        const int t = c >> 1, phase = c & 1;
        const int hid = 32*t + 8*(m >> 2) + (m & 3) + 4*phase;
        #pragma unroll
        for (int j = 0; j < 8; ++j) {
            const int k = kq*8 + j;
            dst[j] = (__fp16)((k < 10) ? w1c_at(k, hid, W1m, b1m, W1g, b1g, W1k, b1k) : 0.f);
        }
    } else {
        const int t = c - NCH1;
        #pragma unroll
        for (int j = 0; j < 8; ++j) {
            const int hid = 32*t + kq*8 + j;
            float v = 0.f;
            if (hid < 512)       { if (m < 9)             v = W2m[hid*9 + m]; }
            else if (hid < 1024) { if (m >= 9 && m < 12)  v = W2g[(hid-512)*3 + (m-9)]; }
            else                 { if (m >= 12 && m < 15) v = W2k[(hid-1024)*3 + (m-12)]; }
            dst[j] = (__fp16)v;
        }
    }
}

__global__ __launch_bounds__(256, 8) void dyn_kernel(
    const __fp16* __restrict__ frag,
    const float* __restrict__ q, const float* __restrict__ q_dot,
    const float* __restrict__ s, const float* __restrict__ s_Ddot,
    const float* __restrict__ tau,
    const float* __restrict__ fv, const float* __restrict__ fc,
    const float* __restrict__ b2m, const float* __restrict__ b2g,
    const float* __restrict__ b2k,
    float* __restrict__ out, int n)
{
    // Partial-sum buffers: one per half. Stride 20 -> aligned b128, no conflicts.
    __shared__ float bufA[2][32][20];
    __shared__ float bufB[2][32][20];

    const int lane = threadIdx.x & 63;
    const int w    = threadIdx.x >> 6;
    const int pair = w >> 1;          // wave pair: shares 32 samples
    const int half = w & 1;           // 0: t=0..23, 1: t=24..47
    const int col  = lane & 15;
    const int quad = lane >> 4;
    const int base32 = blockIdx.x * 64 + pair * 32;   // 64 samples per block

    // B-operands for GEMM1': B[k=quad*8+j][n=sample=col], one per tile.
    h8 ax0, ax1;
    {
        int sm = base32 + col; if (sm >= n) sm = n - 1;
        const float q0 = q[3*sm+0], q1 = q[3*sm+1], q2 = q[3*sm+2];
        const float s0 = s[3*sm+0], s1 = s[3*sm+1], s2 = s[3*sm+2];
        const float d0 = s_Ddot[3*sm+0], d1 = s_Ddot[3*sm+1], d2 = s_Ddot[3*sm+2];
        const bool z0 = (quad == 0), z1 = (quad == 1);
        ax0[0] = (__fp16)(z0 ? q0 : (z1 ? d2  : 0.f));
        ax0[1] = (__fp16)(z0 ? q1 : (z1 ? 1.f : 0.f));
        ax0[2] = (__fp16)(z0 ? q2 : 0.f);
        ax0[3] = (__fp16)(z0 ? s0 : 0.f);
        ax0[4] = (__fp16)(z0 ? s1 : 0.f);
        ax0[5] = (__fp16)(z0 ? s2 : 0.f);
        ax0[6] = (__fp16)(z0 ? d0 : 0.f);
        ax0[7] = (__fp16)(z0 ? d1 : 0.f);
    }
    {
        int sm = base32 + 16 + col; if (sm >= n) sm = n - 1;
        const float q0 = q[3*sm+0], q1 = q[3*sm+1], q2 = q[3*sm+2];
        const float s0 = s[3*sm+0], s1 = s[3*sm+1], s2 = s[3*sm+2];
        const float d0 = s_Ddot[3*sm+0], d1 = s_Ddot[3*sm+1], d2 = s_Ddot[3*sm+2];
        const bool z0 = (quad == 0), z1 = (quad == 1);
        ax1[0] = (__fp16)(z0 ? q0 : (z1 ? d2  : 0.f));
        ax1[1] = (__fp16)(z0 ? q1 : (z1 ? 1.f : 0.f));
        ax1[2] = (__fp16)(z0 ? q2 : 0.f);
        ax1[3] = (__fp16)(z0 ? s0 : 0.f);
        ax1[4] = (__fp16)(z0 ? s1 : 0.f);
        ax1[5] = (__fp16)(z0 ? s2 : 0.f);
        ax1[6] = (__fp16)(z0 ? d0 : 0.f);
        ax1[7] = (__fp16)(z0 ? d1 : 0.f);
    }

    const f32x4 zero4 = {0.f, 0.f, 0.f, 0.f};
    f32x4 acc0 = zero4, acc1 = zero4;

    // Each half-wave covers 24 t-chunks: half 0 -> chunks [0,48) of frag1,
    // half 1 -> chunks [48,96) and frag2 chunks [24,48).
    const h8* p1 = (const h8*)frag + lane + (size_t)half * (48 * 64);
    const h8* p2 = (const h8*)frag + (size_t)NCH1 * 64 + lane + (size_t)half * (NCHH * 64);

// One t-step (verbatim R12): per tile 2 GEMM1' MFMAs -> 4 packed tanh ->
// 1 GEMM2 MFMA; 2 tiles share the weight fragments. Zero LDS in the loop.
#define BODY(W1A, W1B, W2V) do {                                              \
        f32x4 pa0 = __builtin_amdgcn_mfma_f32_16x16x32_f16((W1A), ax0, zero4, 0, 0, 0); \
        f32x4 pb0 = __builtin_amdgcn_mfma_f32_16x16x32_f16((W1B), ax0, zero4, 0, 0, 0); \
        f32x4 pa1 = __builtin_amdgcn_mfma_f32_16x16x32_f16((W1A), ax1, zero4, 0, 0, 0); \
        f32x4 pb1 = __builtin_amdgcn_mfma_f32_16x16x32_f16((W1B), ax1, zero4, 0, 0, 0); \
        u32x4 uv;                                                             \
        uv[0] = __builtin_bit_cast(unsigned int, tanh2(f2h2(pa0[0], pa0[1]))); \
        uv[1] = __builtin_bit_cast(unsigned int, tanh2(f2h2(pa0[2], pa0[3]))); \
        uv[2] = __builtin_bit_cast(unsigned int, tanh2(f2h2(pb0[0], pb0[1]))); \
        uv[3] = __builtin_bit_cast(unsigned int, tanh2(f2h2(pb0[2], pb0[3]))); \
        acc0 = __builtin_amdgcn_mfma_f32_16x16x32_f16((W2V), __builtin_bit_cast(h8, uv), acc0, 0, 0, 0); \
        uv[0] = __builtin_bit_cast(unsigned int, tanh2(f2h2(pa1[0], pa1[1]))); \
        uv[1] = __builtin_bit_cast(unsigned int, tanh2(f2h2(pa1[2], pa1[3]))); \
        uv[2] = __builtin_bit_cast(unsigned int, tanh2(f2h2(pb1[0], pb1[1]))); \
        uv[3] = __builtin_bit_cast(unsigned int, tanh2(f2h2(pb1[2], pb1[3]))); \
        acc1 = __builtin_amdgcn_mfma_f32_16x16x32_f16((W2V), __builtin_bit_cast(h8, uv), acc1, 0, 0, 0); \
    } while (0)

    // Unroll-by-2 ping-pong prefetch; all offsets immediates (< 4096 B).
    h8 a0 = p1[0], b0 = p1[64], c0 = p2[0];
    int t = 0;
    for (; t < NCHH - 2; t += 2) {
        h8 a1 = p1[128], b1 = p1[192], c1 = p2[64];
        p1 += 256; p2 += 128;
        BODY(a0, b0, c0);
        a0 = p1[0]; b0 = p1[64]; c0 = p2[0];
        BODY(a1, b1, c1);
    }
    {   // final pair: no t+2 prefetch -> stays within this half's chunk range
        h8 a1 = p1[128], b1 = p1[192], c1 = p2[64];
        BODY(a0, b0, c0);
        BODY(a1, b1, c1);
    }
#undef BODY

    // Deposit partials: acc lane (col=sample, quad) holds outs {4q..4q+3}.
    {
        float (*mybuf)[32][20] = half ? bufB : bufA;
        *(f32x4*)(&mybuf[pair][col][4*quad])      = acc0;
        *(f32x4*)(&mybuf[pair][16 + col][4*quad]) = acc1;
    }
    __syncthreads();

    // Half-1 waves merge the two halves and finalize: 2 waves x 32 lanes
    // cover the block's 64 samples.
    if (half == 1 && lane < 32) {
        const int i = base32 + lane;
        if (i < n) {
            const float* RA = bufA[pair][lane];
            const float* RB = bufB[pair][lane];
            const float bM0 = RA[0]  + RB[0]  + b2m[0];
            const float bM1 = RA[1]  + RB[1]  + b2m[1];
            const float bM2 = RA[2]  + RB[2]  + b2m[2];
            const float bM3 = RA[3]  + RB[3]  + b2m[3];
            const float bM4 = RA[4]  + RB[4]  + b2m[4];
            const float bM5 = RA[5]  + RB[5]  + b2m[5];
            const float bM6 = RA[6]  + RB[6]  + b2m[6];
            const float bM7 = RA[7]  + RB[7]  + b2m[7];
            const float bM8 = RA[8]  + RB[8]  + b2m[8];
            const float bG0 = RA[9]  + RB[9]  + b2g[0];
            const float bG1 = RA[10] + RB[10] + b2g[1];
            const float bG2 = RA[11] + RB[11] + b2g[2];
            const float bK0 = RA[12] + RB[12] + b2k[0];
            const float bK1 = RA[13] + RB[13] + b2k[1];
            const float bK2 = RA[14] + RB[14] + b2k[2];

            // M = Mraw @ Mraw^T + eps*I
            const float m00 = bM0*bM0 + bM1*bM1 + bM2*bM2 + EPS_DIAG;
            const float m01 = bM0*bM3 + bM1*bM4 + bM2*bM5;
            const float m02 = bM0*bM6 + bM1*bM7 + bM2*bM8;
            const float m11 = bM3*bM3 + bM4*bM4 + bM5*bM5 + EPS_DIAG;
            const float m12 = bM3*bM6 + bM4*bM7 + bM5*bM8;
            const float m22 = bM6*bM6 + bM7*bM7 + bM8*bM8 + EPS_DIAG;

            // rhs = -G + KAB - fv*q_dot - fc*sign(q_dot) + tau
            const float qd0 = q_dot[3*i+0], qd1 = q_dot[3*i+1], qd2 = q_dot[3*i+2];
            const float t0 = tau[3*i+0], t1 = tau[3*i+1], t2 = tau[3*i+2];
            const float fv0 = fv[0], fv1 = fv[1], fv2 = fv[2];
            const float fc0 = fc[0], fc1 = fc[1], fc2 = fc[2];
            const float sg0 = (qd0 > 0.f) ? 1.f : ((qd0 < 0.f) ? -1.f : 0.f);
            const float sg1 = (qd1 > 0.f) ? 1.f : ((qd1 < 0.f) ? -1.f : 0.f);
            const float sg2 = (qd2 > 0.f) ? 1.f : ((qd2 < 0.f) ? -1.f : 0.f);
            const float r0 = -bG0 + bK0 - fv0*qd0 - fc0*sg0 + t0;
            const float r1 = -bG1 + bK1 - fv1*qd1 - fc1*sg1 + t1;
            const float r2 = -bG2 + bK2 - fv2*qd2 - fc2*sg2 + t2;

            // Symmetric 3x3 inverse via adjugate (M SPD, det >= ~1e-3).
            const float c00 = m11*m22 - m12*m12;
            const float c01 = m02*m12 - m01*m22;
            const float c02 = m01*m12 - m02*m11;
            const float det = m00*c00 + m01*c01 + m02*c02;
            const float idet = 1.0f / det;
            const float i11 = m00*m22 - m02*m02;
            const float i12 = m01*m02 - m00*m12;
            const float i22 = m00*m11 - m01*m01;

            out[3*i+0] = (c00*r0 + c01*r1 + c02*r2) * idet;
            out[3*i+1] = (c01*r0 + i11*r1 + i12*r2) * idet;
            out[3*i+2] = (c02*r0 + i12*r1 + i22*r2) * idet;
        }
    }
}

extern "C" void kernel_launch(void* const* d_in, const int* in_sizes, int n_in,
                              void* d_out, int out_size, void* d_ws, size_t ws_size,
                              hipStream_t stream) {
    const float* q      = (const float*)d_in[0];
    const float* q_dot  = (const float*)d_in[1];
    const float* s      = (const float*)d_in[2];
    const float* s_Ddot = (const float*)d_in[3];
    const float* tau    = (const float*)d_in[4];
    const float* fv     = (const float*)d_in[5];
    const float* fc     = (const float*)d_in[6];
    const float* W1m    = (const float*)d_in[7];
    const float* b1m    = (const float*)d_in[8];
    const float* W2m    = (const float*)d_in[9];
    const float* b2m    = (const float*)d_in[10];
    const float* W1g    = (const float*)d_in[11];
    const float* b1g    = (const float*)d_in[12];
    const float* W2g    = (const float*)d_in[13];
    const float* b2g    = (const float*)d_in[14];
    const float* W1k    = (const float*)d_in[15];
    const float* b1k    = (const float*)d_in[16];
    const float* W2k    = (const float*)d_in[17];
    const float* b2k    = (const float*)d_in[18];
    float* out = (float*)d_out;
    __fp16* frag = (__fp16*)d_ws;   // (96+48)*64*8*2 = 147456 B

    const int n = in_sizes[0] / 3;  // B = 131072

    pack_frags<<<((NCH1 + NCH2) * 64 + 255) / 256, 256, 0, stream>>>(
        W1m, b1m, W2m, W1g, b1g, W2g, W1k, b1k, W2k, frag);

    const int blocks = (n + 63) / 64;   // 64 samples per block (2 wave-pairs)
    dyn_kernel<<<blocks, 256, 0, stream>>>(frag, q, q_dot, s, s_Ddot, tau, fv, fc,
                                           b2m, b2g, b2k, out, n);
}